// Round 1
// baseline (1086.051 us; speedup 1.0000x reference)
//
#include <hip/hip_runtime.h>
#include <hip/hip_bf16.h>
#include <cstdint>

#define NN 8192
#define EE 128
#define AA 8
#define QSCALE 0.08838834764831845f   // 1/sqrt(128)

typedef __attribute__((ext_vector_type(8))) short bf16x8;
typedef __attribute__((ext_vector_type(4))) float f32x4;
typedef unsigned short u16;
typedef unsigned int u32;

__device__ __forceinline__ u16 bf16_bits(float x) {
    union { float f; u32 u; } v; v.f = x;
    u32 r = v.u + 0x7fffu + ((v.u >> 16) & 1u);   // RNE
    return (u16)(r >> 16);
}

// ---------------------------------------------------------------------------
// Kernel 1: h = relu(state@w1+b1)@w2+b2 ; q = (h@wq)/sqrt(E) ; k = h@wk
// Writes q,k as bf16 [N][E] and hT as bf16 [E][N].
// 128 threads, 16 rows/block. Thread t: rows {2*(t>>4), +1}, cols (t&15)*8..+8
// => 16 FMAs per 2 LDS broadcast reads (not LDS-bound).
// ---------------------------------------------------------------------------
__global__ __launch_bounds__(128) void k_mlp(
    const float* __restrict__ state,
    const float* __restrict__ w1, const float* __restrict__ b1,
    const float* __restrict__ w2, const float* __restrict__ b2,
    const float* __restrict__ wq, const float* __restrict__ wk,
    u16* __restrict__ qb, u16* __restrict__ kb, u16* __restrict__ hT)
{
    __shared__ float st[16][EE + 1];   // state tile, then reused for h
    __shared__ float h1[16][EE + 1];
    const int t  = threadIdx.x;
    const int rg = t >> 4;            // 0..7
    const int ec = (t & 15) * 8;      // col base
    const int ra = rg * 2, rb = ra + 1;
    const int r0b = blockIdx.x * 16;

    #pragma unroll
    for (int r = 0; r < 16; ++r)
        st[r][t] = state[(size_t)(r0b + r) * EE + t];
    __syncthreads();

    // stage 1: h1 = relu(st@w1 + b1)
    {
        float a0[8], a1[8];
        #pragma unroll
        for (int j = 0; j < 8; ++j) { float b = b1[ec + j]; a0[j] = b; a1[j] = b; }
        for (int s = 0; s < EE; ++s) {
            float x0 = st[ra][s], x1 = st[rb][s];
            const float* wrow = w1 + s * EE + ec;
            #pragma unroll
            for (int j = 0; j < 8; ++j) { float w = wrow[j]; a0[j] = fmaf(x0, w, a0[j]); a1[j] = fmaf(x1, w, a1[j]); }
        }
        __syncthreads();   // all reads of st done before h1 written? (h1 separate; sync guards st reuse below)
        #pragma unroll
        for (int j = 0; j < 8; ++j) { h1[ra][ec + j] = fmaxf(a0[j], 0.f); h1[rb][ec + j] = fmaxf(a1[j], 0.f); }
    }
    __syncthreads();

    // stage 2: h = h1@w2 + b2  (write into st, keep local copy for hT)
    float hva[8], hvb[8];
    {
        float a0[8], a1[8];
        #pragma unroll
        for (int j = 0; j < 8; ++j) { float b = b2[ec + j]; a0[j] = b; a1[j] = b; }
        for (int s = 0; s < EE; ++s) {
            float x0 = h1[ra][s], x1 = h1[rb][s];
            const float* wrow = w2 + s * EE + ec;
            #pragma unroll
            for (int j = 0; j < 8; ++j) { float w = wrow[j]; a0[j] = fmaf(x0, w, a0[j]); a1[j] = fmaf(x1, w, a1[j]); }
        }
        #pragma unroll
        for (int j = 0; j < 8; ++j) {
            st[ra][ec + j] = a0[j]; st[rb][ec + j] = a1[j];
            hva[j] = a0[j]; hvb[j] = a1[j];
        }
    }
    __syncthreads();

    // stage 3: q = (h@wq)*QSCALE, k = h@wk   (h now lives in st)
    {
        float q0[8], q1[8], k0[8], k1[8];
        #pragma unroll
        for (int j = 0; j < 8; ++j) { q0[j] = 0.f; q1[j] = 0.f; k0[j] = 0.f; k1[j] = 0.f; }
        for (int s = 0; s < EE; ++s) {
            float x0 = st[ra][s], x1 = st[rb][s];
            const float* wqr = wq + s * EE + ec;
            const float* wkr = wk + s * EE + ec;
            #pragma unroll
            for (int j = 0; j < 8; ++j) {
                float a = wqr[j], b = wkr[j];
                q0[j] = fmaf(x0, a, q0[j]); q1[j] = fmaf(x1, a, q1[j]);
                k0[j] = fmaf(x0, b, k0[j]); k1[j] = fmaf(x1, b, k1[j]);
            }
        }
        bf16x8 vq0, vq1, vk0, vk1;
        #pragma unroll
        for (int j = 0; j < 8; ++j) {
            vq0[j] = (short)bf16_bits(q0[j] * QSCALE);
            vq1[j] = (short)bf16_bits(q1[j] * QSCALE);
            vk0[j] = (short)bf16_bits(k0[j]);
            vk1[j] = (short)bf16_bits(k1[j]);
        }
        *reinterpret_cast<bf16x8*>(qb + (size_t)(r0b + ra) * EE + ec) = vq0;
        *reinterpret_cast<bf16x8*>(qb + (size_t)(r0b + rb) * EE + ec) = vq1;
        *reinterpret_cast<bf16x8*>(kb + (size_t)(r0b + ra) * EE + ec) = vk0;
        *reinterpret_cast<bf16x8*>(kb + (size_t)(r0b + rb) * EE + ec) = vk1;
    }

    // hT[e][n]: pack the 2 consecutive rows into one 4B store per col
    #pragma unroll
    for (int j = 0; j < 8; ++j) {
        u32 pack = (u32)bf16_bits(hva[j]) | ((u32)bf16_bits(hvb[j]) << 16);
        *reinterpret_cast<u32*>(hT + (size_t)(ec + j) * NN + r0b + ra) = pack;
    }
}

// ---------------------------------------------------------------------------
// Kernel 2: flash-style masked attention.  agg = softmax(mask(q@k^T))@h
// 128 threads = 2 waves; wave handles 16 q-rows; KV chunks of 64.
// MFMA 16x16x32 bf16. C/D layout: col=lane&15, row=4*(lane>>4)+j.
// A/B frag: row(col)=lane&15, k = 8*(lane>>4)+i (i contiguous, 16B loads).
// ---------------------------------------------------------------------------
__global__ __launch_bounds__(128) void k_attn(
    const u16* __restrict__ qb, const u16* __restrict__ kb,
    const u16* __restrict__ hT, const int* __restrict__ adj,
    float* __restrict__ agg)
{
    __shared__ u16 plds[2][16][64];   // per-wave P tile, XOR-swizzled
    const int tid  = threadIdx.x;
    const int wv   = tid >> 6;
    const int lane = tid & 63;
    const int l15  = lane & 15;
    const int g    = lane >> 4;
    const int qbase = blockIdx.x * 32 + wv * 16;

    // Q fragments stay in registers for the whole kernel
    bf16x8 qf[4];
    #pragma unroll
    for (int ks = 0; ks < 4; ++ks)
        qf[ks] = *reinterpret_cast<const bf16x8*>(qb + (size_t)(qbase + l15) * EE + ks * 32 + g * 8);

    f32x4 acc[8];
    #pragma unroll
    for (int et = 0; et < 8; ++et) acc[et] = f32x4{0.f, 0.f, 0.f, 0.f};
    float m[4], l[4];
    #pragma unroll
    for (int j = 0; j < 4; ++j) { m[j] = -__builtin_inff(); l[j] = 0.f; }

    const int* adjbase = adj + (size_t)(qbase + g * 4) * NN;

    for (int c0 = 0; c0 < NN; c0 += 64) {
        // S = q @ k^T  (pre-scaled q)
        f32x4 sv[4];
        #pragma unroll
        for (int nt = 0; nt < 4; ++nt) sv[nt] = f32x4{0.f, 0.f, 0.f, 0.f};
        #pragma unroll
        for (int nt = 0; nt < 4; ++nt) {
            #pragma unroll
            for (int ks = 0; ks < 4; ++ks) {
                bf16x8 bk = *reinterpret_cast<const bf16x8*>(
                    kb + (size_t)(c0 + nt * 16 + l15) * EE + ks * 32 + g * 8);
                sv[nt] = __builtin_amdgcn_mfma_f32_16x16x32_bf16(qf[ks], bk, sv[nt], 0, 0, 0);
            }
        }
        // adjacency mask
        float ms[4][4];
        #pragma unroll
        for (int nt = 0; nt < 4; ++nt) {
            #pragma unroll
            for (int j = 0; j < 4; ++j) {
                int a = adjbase[(size_t)j * NN + c0 + nt * 16 + l15];
                ms[nt][j] = a ? sv[nt][j] : -__builtin_inff();
            }
        }
        // online softmax: row max over 64 cols (4 in-lane + 16-lane shfl tree)
        float alpha[4], mn[4];
        #pragma unroll
        for (int j = 0; j < 4; ++j) {
            float rm = fmaxf(fmaxf(ms[0][j], ms[1][j]), fmaxf(ms[2][j], ms[3][j]));
            rm = fmaxf(rm, __shfl_xor(rm, 1));
            rm = fmaxf(rm, __shfl_xor(rm, 2));
            rm = fmaxf(rm, __shfl_xor(rm, 4));
            rm = fmaxf(rm, __shfl_xor(rm, 8));
            mn[j] = fmaxf(m[j], rm);
            alpha[j] = (mn[j] == m[j]) ? 1.f : __expf(m[j] - mn[j]);  // no NaN for -inf==-inf
            m[j] = mn[j];
        }
        float rs[4] = {0.f, 0.f, 0.f, 0.f};
        u16 pb[4][4];
        #pragma unroll
        for (int nt = 0; nt < 4; ++nt) {
            #pragma unroll
            for (int j = 0; j < 4; ++j) {
                float pv = (mn[j] == -__builtin_inff()) ? 0.f : __expf(ms[nt][j] - mn[j]);
                rs[j] += pv;
                pb[nt][j] = bf16_bits(pv);
            }
        }
        #pragma unroll
        for (int j = 0; j < 4; ++j) {
            float r = rs[j];
            r += __shfl_xor(r, 1);
            r += __shfl_xor(r, 2);
            r += __shfl_xor(r, 4);
            r += __shfl_xor(r, 8);
            l[j] = l[j] * alpha[j] + r;
        }
        // P (D-layout) -> LDS -> A-frag layout.  XOR swizzle elem ^= (row&7)<<3.
        #pragma unroll
        for (int nt = 0; nt < 4; ++nt) {
            #pragma unroll
            for (int j = 0; j < 4; ++j) {
                int row = g * 4 + j;
                int col = nt * 16 + l15;
                plds[wv][row][col ^ ((row & 7) << 3)] = pb[nt][j];
            }
        }
        asm volatile("s_waitcnt lgkmcnt(0)" ::: "memory");
        __builtin_amdgcn_sched_barrier(0);
        bf16x8 pa[2];
        #pragma unroll
        for (int ks = 0; ks < 2; ++ks) {
            int eo = (ks * 32 + g * 8) ^ ((l15 & 7) << 3);
            pa[ks] = *reinterpret_cast<const bf16x8*>(&plds[wv][l15][eo]);
        }
        __builtin_amdgcn_sched_barrier(0);
        // rescale + PV:  acc += P @ h_chunk   (B-frags contiguous via hT)
        f32x4 av = {alpha[0], alpha[1], alpha[2], alpha[3]};
        #pragma unroll
        for (int et = 0; et < 8; ++et) {
            acc[et] = acc[et] * av;
            #pragma unroll
            for (int ks = 0; ks < 2; ++ks) {
                bf16x8 bh = *reinterpret_cast<const bf16x8*>(
                    hT + (size_t)(et * 16 + l15) * NN + c0 + ks * 32 + g * 8);
                acc[et] = __builtin_amdgcn_mfma_f32_16x16x32_bf16(pa[ks], bh, acc[et], 0, 0, 0);
            }
        }
    }
    float inv[4];
    #pragma unroll
    for (int j = 0; j < 4; ++j) inv[j] = 1.f / l[j];
    #pragma unroll
    for (int et = 0; et < 8; ++et) {
        #pragma unroll
        for (int j = 0; j < 4; ++j)
            agg[(size_t)(qbase + g * 4 + j) * EE + et * 16 + l15] = acc[et][j] * inv[j];
    }
}

// ---------------------------------------------------------------------------
// Kernel 3: out = relu(agg@wh1+bh1)@wh2 + bh2
// ---------------------------------------------------------------------------
__global__ __launch_bounds__(128) void k_head(
    const float* __restrict__ agg,
    const float* __restrict__ wh1, const float* __restrict__ bh1,
    const float* __restrict__ wh2, const float* __restrict__ bh2,
    float* __restrict__ out)
{
    __shared__ float ag[16][EE + 1];
    __shared__ float h2[16][EE + 1];
    const int t  = threadIdx.x;
    const int rg = t >> 4;
    const int ec = (t & 15) * 8;
    const int ra = rg * 2, rb = ra + 1;
    const int r0b = blockIdx.x * 16;

    #pragma unroll
    for (int r = 0; r < 16; ++r)
        ag[r][t] = agg[(size_t)(r0b + r) * EE + t];
    __syncthreads();
    {
        float a0[8], a1[8];
        #pragma unroll
        for (int j = 0; j < 8; ++j) { float b = bh1[ec + j]; a0[j] = b; a1[j] = b; }
        for (int s = 0; s < EE; ++s) {
            float x0 = ag[ra][s], x1 = ag[rb][s];
            const float* wrow = wh1 + s * EE + ec;
            #pragma unroll
            for (int j = 0; j < 8; ++j) { float w = wrow[j]; a0[j] = fmaf(x0, w, a0[j]); a1[j] = fmaf(x1, w, a1[j]); }
        }
        #pragma unroll
        for (int j = 0; j < 8; ++j) { h2[ra][ec + j] = fmaxf(a0[j], 0.f); h2[rb][ec + j] = fmaxf(a1[j], 0.f); }
    }
    __syncthreads();
    const int r = t >> 3, a = t & 7;
    float o = bh2[a];
    for (int s = 0; s < EE; ++s) o = fmaf(h2[r][s], wh2[s * AA + a], o);
    out[(size_t)(r0b + r) * AA + a] = o;
}

// ---------------------------------------------------------------------------
extern "C" void kernel_launch(void* const* d_in, const int* in_sizes, int n_in,
                              void* d_out, int out_size, void* d_ws, size_t ws_size,
                              hipStream_t stream)
{
    (void)in_sizes; (void)n_in; (void)out_size; (void)ws_size;
    const float* state = (const float*)d_in[0];
    const int*   adj   = (const int*)d_in[1];
    const float* w1  = (const float*)d_in[2];
    const float* b1  = (const float*)d_in[3];
    const float* w2  = (const float*)d_in[4];
    const float* b2  = (const float*)d_in[5];
    const float* wq  = (const float*)d_in[6];
    const float* wk  = (const float*)d_in[7];
    const float* wh1 = (const float*)d_in[8];
    const float* bh1 = (const float*)d_in[9];
    const float* wh2 = (const float*)d_in[10];
    const float* bh2 = (const float*)d_in[11];
    float* out = (float*)d_out;

    char* ws = (char*)d_ws;
    u16*  qb  = (u16*)ws;                                  // 2 MB
    u16*  kb  = (u16*)(ws + (size_t)NN * EE * 2);          // 2 MB
    u16*  hT  = (u16*)(ws + (size_t)NN * EE * 4);          // 2 MB
    float* agg = (float*)(ws + (size_t)NN * EE * 6);       // 4 MB

    k_mlp <<<NN / 16, 128, 0, stream>>>(state, w1, b1, w2, b2, wq, wk, qb, kb, hT);
    k_attn<<<NN / 32, 128, 0, stream>>>(qb, kb, hT, adj, agg);
    k_head<<<NN / 16, 128, 0, stream>>>(agg, wh1, bh1, wh2, bh2, out);
}

// Round 4
// 325.148 us; speedup vs baseline: 3.3402x; 3.3402x over previous
//
#include <hip/hip_runtime.h>
#include <hip/hip_bf16.h>
#include <cstdint>

#define NN 8192
#define EE 128
#define AA 8
#define QSCALE 0.08838834764831845f   // 1/sqrt(128)
#define KVW 8                          // waves per block = KV partitions
#define KVLEN (NN / KVW)               // 1024 cols per wave

typedef __attribute__((ext_vector_type(8))) short bf16x8;
typedef __attribute__((ext_vector_type(4))) float f32x4;
typedef unsigned short u16;
typedef unsigned int u32;

__device__ __forceinline__ u16 bf16_bits(float x) {
    union { float f; u32 u; } v; v.f = x;
    u32 r = v.u + 0x7fffu + ((v.u >> 16) & 1u);   // RNE
    return (u16)(r >> 16);
}

// ---------------------------------------------------------------------------
// Kernel 1: h = relu(state@w1+b1)@w2+b2 ; q = (h@wq)/sqrt(E) ; k = h@wk
// Writes q,k as bf16 [N][E] and hT as bf16 [E][N].
// ---------------------------------------------------------------------------
__global__ __launch_bounds__(128) void k_mlp(
    const float* __restrict__ state,
    const float* __restrict__ w1, const float* __restrict__ b1,
    const float* __restrict__ w2, const float* __restrict__ b2,
    const float* __restrict__ wq, const float* __restrict__ wk,
    u16* __restrict__ qb, u16* __restrict__ kb, u16* __restrict__ hT)
{
    __shared__ float st[16][EE + 1];   // state tile, then reused for h
    __shared__ float h1[16][EE + 1];
    const int t  = threadIdx.x;
    const int rg = t >> 4;            // 0..7
    const int ec = (t & 15) * 8;      // col base
    const int ra = rg * 2, rb = ra + 1;
    const int r0b = blockIdx.x * 16;

    #pragma unroll
    for (int r = 0; r < 16; ++r)
        st[r][t] = state[(size_t)(r0b + r) * EE + t];
    __syncthreads();

    // stage 1: h1 = relu(st@w1 + b1)
    {
        float a0[8], a1[8];
        #pragma unroll
        for (int j = 0; j < 8; ++j) { float b = b1[ec + j]; a0[j] = b; a1[j] = b; }
        for (int s = 0; s < EE; ++s) {
            float x0 = st[ra][s], x1 = st[rb][s];
            const float* wrow = w1 + s * EE + ec;
            #pragma unroll
            for (int j = 0; j < 8; ++j) { float w = wrow[j]; a0[j] = fmaf(x0, w, a0[j]); a1[j] = fmaf(x1, w, a1[j]); }
        }
        __syncthreads();
        #pragma unroll
        for (int j = 0; j < 8; ++j) { h1[ra][ec + j] = fmaxf(a0[j], 0.f); h1[rb][ec + j] = fmaxf(a1[j], 0.f); }
    }
    __syncthreads();

    // stage 2: h = h1@w2 + b2
    float hva[8], hvb[8];
    {
        float a0[8], a1[8];
        #pragma unroll
        for (int j = 0; j < 8; ++j) { float b = b2[ec + j]; a0[j] = b; a1[j] = b; }
        for (int s = 0; s < EE; ++s) {
            float x0 = h1[ra][s], x1 = h1[rb][s];
            const float* wrow = w2 + s * EE + ec;
            #pragma unroll
            for (int j = 0; j < 8; ++j) { float w = wrow[j]; a0[j] = fmaf(x0, w, a0[j]); a1[j] = fmaf(x1, w, a1[j]); }
        }
        #pragma unroll
        for (int j = 0; j < 8; ++j) {
            st[ra][ec + j] = a0[j]; st[rb][ec + j] = a1[j];
            hva[j] = a0[j]; hvb[j] = a1[j];
        }
    }
    __syncthreads();

    // stage 3: q = (h@wq)*QSCALE, k = h@wk
    {
        float q0[8], q1[8], k0[8], k1[8];
        #pragma unroll
        for (int j = 0; j < 8; ++j) { q0[j] = 0.f; q1[j] = 0.f; k0[j] = 0.f; k1[j] = 0.f; }
        for (int s = 0; s < EE; ++s) {
            float x0 = st[ra][s], x1 = st[rb][s];
            const float* wqr = wq + s * EE + ec;
            const float* wkr = wk + s * EE + ec;
            #pragma unroll
            for (int j = 0; j < 8; ++j) {
                float a = wqr[j], b = wkr[j];
                q0[j] = fmaf(x0, a, q0[j]); q1[j] = fmaf(x1, a, q1[j]);
                k0[j] = fmaf(x0, b, k0[j]); k1[j] = fmaf(x1, b, k1[j]);
            }
        }
        bf16x8 vq0, vq1, vk0, vk1;
        #pragma unroll
        for (int j = 0; j < 8; ++j) {
            vq0[j] = (short)bf16_bits(q0[j] * QSCALE);
            vq1[j] = (short)bf16_bits(q1[j] * QSCALE);
            vk0[j] = (short)bf16_bits(k0[j]);
            vk1[j] = (short)bf16_bits(k1[j]);
        }
        *reinterpret_cast<bf16x8*>(qb + (size_t)(r0b + ra) * EE + ec) = vq0;
        *reinterpret_cast<bf16x8*>(qb + (size_t)(r0b + rb) * EE + ec) = vq1;
        *reinterpret_cast<bf16x8*>(kb + (size_t)(r0b + ra) * EE + ec) = vk0;
        *reinterpret_cast<bf16x8*>(kb + (size_t)(r0b + rb) * EE + ec) = vk1;
    }

    #pragma unroll
    for (int j = 0; j < 8; ++j) {
        u32 pack = (u32)bf16_bits(hva[j]) | ((u32)bf16_bits(hvb[j]) << 16);
        *reinterpret_cast<u32*>(hT + (size_t)(ec + j) * NN + r0b + ra) = pack;
    }
}

// ---------------------------------------------------------------------------
// Kernel 2: flash-style masked attention with block-level KV split.
// Block = 512 threads = 8 waves, one 16-q-row tile per block.
// Wave w handles KV cols [w*1024, (w+1)*1024) with flash partials (m,l,acc),
// partials combined through LDS at the end.
// Grid = 512 blocks -> 2 blocks/CU x 8 waves = 16 waves/CU (50% occupancy).
// ---------------------------------------------------------------------------
__global__ __launch_bounds__(512, 4) void k_attn(
    const u16* __restrict__ qb, const u16* __restrict__ kb,
    const u16* __restrict__ hT, const int* __restrict__ adj,
    float* __restrict__ agg)
{
    __shared__ float lds_acc[KVW][16][EE];   // 64 KB; first 2KB of each wave's
                                             // slot doubles as its P tile
    __shared__ float lds_m[KVW][16];
    __shared__ float lds_l[KVW][16];

    const int tid  = threadIdx.x;
    const int wv   = tid >> 6;
    const int lane = tid & 63;
    const int l15  = lane & 15;
    const int g    = lane >> 4;
    const int qbase = blockIdx.x * 16;
    const int kv0   = wv * KVLEN;

    // Q fragments stay in registers for the whole kernel
    bf16x8 qf[4];
    #pragma unroll
    for (int ks = 0; ks < 4; ++ks)
        qf[ks] = *reinterpret_cast<const bf16x8*>(qb + (size_t)(qbase + l15) * EE + ks * 32 + g * 8);

    f32x4 acc[8];
    #pragma unroll
    for (int et = 0; et < 8; ++et) acc[et] = f32x4{0.f, 0.f, 0.f, 0.f};
    float m[4], l[4];
    #pragma unroll
    for (int j = 0; j < 4; ++j) { m[j] = -__builtin_inff(); l[j] = 0.f; }

    const int* adjbase = adj + (size_t)(qbase + g * 4) * NN;
    u16* plw = reinterpret_cast<u16*>(&lds_acc[wv][0][0]);   // [16][64] swizzled

    for (int cc = 0; cc < KVLEN / 64; ++cc) {
        const int c0 = kv0 + cc * 64;
        // hoist adjacency loads (HBM stream) ahead of the MFMAs
        int av[4][4];
        #pragma unroll
        for (int nt = 0; nt < 4; ++nt)
            #pragma unroll
            for (int j = 0; j < 4; ++j)
                av[nt][j] = adjbase[(size_t)j * NN + c0 + nt * 16 + l15];

        // S = q @ k^T  (pre-scaled q)
        f32x4 sv[4];
        #pragma unroll
        for (int nt = 0; nt < 4; ++nt) sv[nt] = f32x4{0.f, 0.f, 0.f, 0.f};
        #pragma unroll
        for (int nt = 0; nt < 4; ++nt) {
            #pragma unroll
            for (int ks = 0; ks < 4; ++ks) {
                bf16x8 bk = *reinterpret_cast<const bf16x8*>(
                    kb + (size_t)(c0 + nt * 16 + l15) * EE + ks * 32 + g * 8);
                sv[nt] = __builtin_amdgcn_mfma_f32_16x16x32_bf16(qf[ks], bk, sv[nt], 0, 0, 0);
            }
        }
        // adjacency mask
        float ms[4][4];
        #pragma unroll
        for (int nt = 0; nt < 4; ++nt)
            #pragma unroll
            for (int j = 0; j < 4; ++j)
                ms[nt][j] = av[nt][j] ? sv[nt][j] : -__builtin_inff();

        // online softmax over this 64-col chunk
        float alpha[4], mn[4];
        #pragma unroll
        for (int j = 0; j < 4; ++j) {
            float rm = fmaxf(fmaxf(ms[0][j], ms[1][j]), fmaxf(ms[2][j], ms[3][j]));
            rm = fmaxf(rm, __shfl_xor(rm, 1));
            rm = fmaxf(rm, __shfl_xor(rm, 2));
            rm = fmaxf(rm, __shfl_xor(rm, 4));
            rm = fmaxf(rm, __shfl_xor(rm, 8));
            mn[j] = fmaxf(m[j], rm);
            alpha[j] = (mn[j] == m[j]) ? 1.f : __expf(m[j] - mn[j]);
            m[j] = mn[j];
        }
        float rs[4] = {0.f, 0.f, 0.f, 0.f};
        u16 pb[4][4];
        #pragma unroll
        for (int nt = 0; nt < 4; ++nt) {
            #pragma unroll
            for (int j = 0; j < 4; ++j) {
                float pv = (mn[j] == -__builtin_inff()) ? 0.f : __expf(ms[nt][j] - mn[j]);
                rs[j] += pv;
                pb[nt][j] = bf16_bits(pv);
            }
        }
        #pragma unroll
        for (int j = 0; j < 4; ++j) {
            float r = rs[j];
            r += __shfl_xor(r, 1);
            r += __shfl_xor(r, 2);
            r += __shfl_xor(r, 4);
            r += __shfl_xor(r, 8);
            l[j] = l[j] * alpha[j] + r;
        }
        // P (D-layout) -> per-wave LDS tile -> A-frag layout (XOR swizzle)
        #pragma unroll
        for (int nt = 0; nt < 4; ++nt) {
            #pragma unroll
            for (int j = 0; j < 4; ++j) {
                int row = g * 4 + j;
                int col = nt * 16 + l15;
                plw[row * 64 + (col ^ ((row & 7) << 3))] = pb[nt][j];
            }
        }
        asm volatile("s_waitcnt lgkmcnt(0)" ::: "memory");
        __builtin_amdgcn_sched_barrier(0);
        bf16x8 pa[2];
        #pragma unroll
        for (int ks = 0; ks < 2; ++ks) {
            int eo = (ks * 32 + g * 8) ^ ((l15 & 7) << 3);
            pa[ks] = *reinterpret_cast<const bf16x8*>(&plw[l15 * 64 + eo]);
        }
        __builtin_amdgcn_sched_barrier(0);
        // rescale + PV:  acc += P @ h_chunk   (B-frags contiguous via hT)
        f32x4 avv = {alpha[0], alpha[1], alpha[2], alpha[3]};
        #pragma unroll
        for (int et = 0; et < 8; ++et) {
            acc[et] = acc[et] * avv;
            #pragma unroll
            for (int ks = 0; ks < 2; ++ks) {
                bf16x8 bh = *reinterpret_cast<const bf16x8*>(
                    hT + (size_t)(et * 16 + l15) * NN + c0 + ks * 32 + g * 8);
                acc[et] = __builtin_amdgcn_mfma_f32_16x16x32_bf16(pa[ks], bh, acc[et], 0, 0, 0);
            }
        }
    }

    // write partials (overwrites this wave's P region -- wave-local, ordered)
    #pragma unroll
    for (int et = 0; et < 8; ++et)
        #pragma unroll
        for (int j = 0; j < 4; ++j)
            lds_acc[wv][g * 4 + j][et * 16 + l15] = acc[et][j];
    if (l15 == 0) {
        #pragma unroll
        for (int j = 0; j < 4; ++j) {
            lds_m[wv][g * 4 + j] = m[j];
            lds_l[wv][g * 4 + j] = l[j];
        }
    }
    __syncthreads();

    // combine 8 partials: wave wv owns rows {2wv, 2wv+1}; lane owns 2 cols
    #pragma unroll
    for (int rr = 0; rr < 2; ++rr) {
        const int r = wv * 2 + rr;
        float mp[KVW], M = -__builtin_inff();
        #pragma unroll
        for (int p = 0; p < KVW; ++p) { mp[p] = lds_m[p][r]; M = fmaxf(M, mp[p]); }
        float ep[KVW], L = 0.f;
        #pragma unroll
        for (int p = 0; p < KVW; ++p) { ep[p] = __expf(mp[p] - M); L += lds_l[p][r] * ep[p]; }
        const float invL = 1.f / L;
        #pragma unroll
        for (int cs = 0; cs < 2; ++cs) {
            const int c = lane + cs * 64;
            float s = 0.f;
            #pragma unroll
            for (int p = 0; p < KVW; ++p) s += lds_acc[p][r][c] * ep[p];
            agg[(size_t)(qbase + r) * EE + c] = s * invL;
        }
    }
}

// ---------------------------------------------------------------------------
// Kernel 3: out = relu(agg@wh1+bh1)@wh2 + bh2
// ---------------------------------------------------------------------------
__global__ __launch_bounds__(128) void k_head(
    const float* __restrict__ agg,
    const float* __restrict__ wh1, const float* __restrict__ bh1,
    const float* __restrict__ wh2, const float* __restrict__ bh2,
    float* __restrict__ out)
{
    __shared__ float ag[16][EE + 1];
    __shared__ float h2[16][EE + 1];
    const int t  = threadIdx.x;
    const int rg = t >> 4;
    const int ec = (t & 15) * 8;
    const int ra = rg * 2, rb = ra + 1;
    const int r0b = blockIdx.x * 16;

    #pragma unroll
    for (int r = 0; r < 16; ++r)
        ag[r][t] = agg[(size_t)(r0b + r) * EE + t];
    __syncthreads();
    {
        float a0[8], a1[8];
        #pragma unroll
        for (int j = 0; j < 8; ++j) { float b = bh1[ec + j]; a0[j] = b; a1[j] = b; }
        for (int s = 0; s < EE; ++s) {
            float x0 = ag[ra][s], x1 = ag[rb][s];
            const float* wrow = wh1 + s * EE + ec;
            #pragma unroll
            for (int j = 0; j < 8; ++j) { float w = wrow[j]; a0[j] = fmaf(x0, w, a0[j]); a1[j] = fmaf(x1, w, a1[j]); }
        }
        #pragma unroll
        for (int j = 0; j < 8; ++j) { h2[ra][ec + j] = fmaxf(a0[j], 0.f); h2[rb][ec + j] = fmaxf(a1[j], 0.f); }
    }
    __syncthreads();
    const int r = t >> 3, a = t & 7;
    float o = bh2[a];
    for (int s = 0; s < EE; ++s) o = fmaf(h2[r][s], wh2[s * AA + a], o);
    out[(size_t)(r0b + r) * AA + a] = o;
}

// ---------------------------------------------------------------------------
extern "C" void kernel_launch(void* const* d_in, const int* in_sizes, int n_in,
                              void* d_out, int out_size, void* d_ws, size_t ws_size,
                              hipStream_t stream)
{
    (void)in_sizes; (void)n_in; (void)out_size; (void)ws_size;
    const float* state = (const float*)d_in[0];
    const int*   adj   = (const int*)d_in[1];
    const float* w1  = (const float*)d_in[2];
    const float* b1  = (const float*)d_in[3];
    const float* w2  = (const float*)d_in[4];
    const float* b2  = (const float*)d_in[5];
    const float* wq  = (const float*)d_in[6];
    const float* wk  = (const float*)d_in[7];
    const float* wh1 = (const float*)d_in[8];
    const float* bh1 = (const float*)d_in[9];
    const float* wh2 = (const float*)d_in[10];
    const float* bh2 = (const float*)d_in[11];
    float* out = (float*)d_out;

    char* ws = (char*)d_ws;
    u16*  qb  = (u16*)ws;                                  // 2 MB
    u16*  kb  = (u16*)(ws + (size_t)NN * EE * 2);          // 2 MB
    u16*  hT  = (u16*)(ws + (size_t)NN * EE * 4);          // 2 MB
    float* agg = (float*)(ws + (size_t)NN * EE * 6);       // 4 MB

    k_mlp <<<NN / 16, 128, 0, stream>>>(state, w1, b1, w2, b2, wq, wk, qb, kb, hT);
    k_attn<<<NN / 16, 512, 0, stream>>>(qb, kb, hT, adj, agg);
    k_head<<<NN / 16, 128, 0, stream>>>(agg, wh1, bh1, wh2, bh2, out);
}